// Round 4
// baseline (40.322 us; speedup 1.0000x reference)
//
#include <hip/hip_runtime.h>

// Problem constants (from reference setup_inputs)
#define BB 4
#define CC 128
#define HH 192
#define WW 256
#define HW (HH * WW)

typedef float floatx4 __attribute__((ext_vector_type(4)));  // native vec for nontemporal

// Pass 1: per-pixel channel reductions -> clamped normalized dot map
// Dc[b,h,w] = max(dot/(|i||e|), 0).
// Block = 64 pixels (16 float4-quads) x 16 channel-chunks of 8 channels.
// Register-staged loads: 16 float4 loads in flight per thread (MLP).
__global__ __launch_bounds__(256) void dotnorm_kernel(
    const float* __restrict__ img, const float* __restrict__ evt,
    float* __restrict__ D)
{
    const int blk = blockIdx.x;            // (b*H + h)*4 + seg
    const int tid = threadIdx.x;
    const int qx  = tid & 15;              // quad within 64-pixel segment
    const int cz  = tid >> 4;              // channel chunk 0..15
    const int seg = blk & 3;
    const int row = blk >> 2;              // b*H + h
    const int b   = row / HH;
    const int h   = row - b * HH;
    const int w0  = seg * 64 + (qx << 2);
    const int base0 = b * CC * HW + h * WW + w0;

    const float* ip = img + base0 + (cz * 8) * HW;
    const float* ep = evt + base0 + (cz * 8) * HW;

    // Stage all 16 loads into registers first -> max memory-level parallelism.
    floatx4 iv[8], ev[8];
    #pragma unroll
    for (int c = 0; c < 8; ++c)
        iv[c] = *reinterpret_cast<const floatx4*>(ip + c * HW);
    #pragma unroll
    for (int c = 0; c < 8; ++c)
        ev[c] = *reinterpret_cast<const floatx4*>(ep + c * HW);

    floatx4 aii = 0.f, aee = 0.f, aie = 0.f;
    #pragma unroll
    for (int c = 0; c < 8; ++c) {
        aii += iv[c] * iv[c];
        aee += ev[c] * ev[c];
        aie += iv[c] * ev[c];
    }

    __shared__ float s_ii[16][64];
    __shared__ float s_ee[16][64];
    __shared__ float s_ie[16][64];
    const int p4 = qx << 2;
    s_ii[cz][p4 + 0] = aii.x; s_ii[cz][p4 + 1] = aii.y; s_ii[cz][p4 + 2] = aii.z; s_ii[cz][p4 + 3] = aii.w;
    s_ee[cz][p4 + 0] = aee.x; s_ee[cz][p4 + 1] = aee.y; s_ee[cz][p4 + 2] = aee.z; s_ee[cz][p4 + 3] = aee.w;
    s_ie[cz][p4 + 0] = aie.x; s_ie[cz][p4 + 1] = aie.y; s_ie[cz][p4 + 2] = aie.z; s_ie[cz][p4 + 3] = aie.w;
    __syncthreads();

    if (tid < 64) {
        float ii = 0.f, ee = 0.f, ie = 0.f;
        #pragma unroll
        for (int k = 0; k < 16; ++k) {
            ii += s_ii[k][tid];
            ee += s_ee[k][tid];
            ie += s_ie[k][tid];
        }
        const float ni = fmaxf(sqrtf(ii), 1e-12f);
        const float ne = fmaxf(sqrtf(ee), 1e-12f);
        // ReLU folded here: borders in pass 2 are zero-filled, and
        // max(Dc,0) == Dc after this clamp.
        D[row * WW + seg * 64 + tid] = fmaxf(ie / (ni * ne), 0.0f);
    }
}

// Pass 2: out[b,k=(i,j),h,w] = Dc[b, h+i-1, w+j-1] (zero outside).
// One thread per 8 output pixels (2 float4 stores); grid = 864 blocks.
__global__ __launch_bounds__(256) void gather_kernel(
    const float* __restrict__ D, float* __restrict__ out)
{
    const int idx  = blockIdx.x * 256 + threadIdx.x;  // output oct index
    const int ox   = idx & 31;            // 8-pixel group within row
    const int rest = idx >> 5;            // (b*9 + k)*H + h
    const int h    = rest % HH;
    const int bk   = rest / HH;
    const int k    = bk % 9;
    const int b    = bk / 9;
    const int i    = k / 3;
    const int j    = k - 3 * i;
    const int w0   = ox << 3;

    const int y   = h + i - 1;
    const bool vy = (y >= 0) && (y < HH);
    const int rowbase = (b * HH + y) * WW;

    float r[8];
    #pragma unroll
    for (int e = 0; e < 8; ++e) {
        const int x = w0 + e + j - 1;
        r[e] = (vy && x >= 0 && x < WW) ? D[rowbase + x] : 0.0f;
    }
    floatx4 o0 = {r[0], r[1], r[2], r[3]};
    floatx4 o1 = {r[4], r[5], r[6], r[7]};
    // Nontemporal: don't evict the L3-resident inputs with the output stream.
    __builtin_nontemporal_store(o0, reinterpret_cast<floatx4*>(out + (size_t)idx * 8));
    __builtin_nontemporal_store(o1, reinterpret_cast<floatx4*>(out + (size_t)idx * 8 + 4));
}

extern "C" void kernel_launch(void* const* d_in, const int* in_sizes, int n_in,
                              void* d_out, int out_size, void* d_ws, size_t ws_size,
                              hipStream_t stream) {
    const float* img = (const float*)d_in[0];
    const float* evt = (const float*)d_in[1];
    float* out = (float*)d_out;
    float* D   = (float*)d_ws;   // needs B*H*W*4 = 3,145,728 bytes

    dotnorm_kernel<<<BB * HH * 4, 256, 0, stream>>>(img, evt, D);
    gather_kernel<<<(BB * 9 * HH * WW / 8) / 256, 256, 0, stream>>>(D, out);
}